// Round 10
// baseline (161.784 us; speedup 1.0000x reference)
//
#include <hip/hip_runtime.h>
#include <stdint.h>

typedef float f32x4 __attribute__((ext_vector_type(4)));
typedef __bf16 bf16x8 __attribute__((ext_vector_type(8)));

#define AS1 __attribute__((address_space(1)))
#define AS3 __attribute__((address_space(3)))

__device__ __forceinline__ unsigned short f2bf(float f) {
  uint32_t u = __builtin_bit_cast(uint32_t, f);
  return (unsigned short)((u + 0x7fffu + ((u >> 16) & 1u)) >> 16);
}
__device__ __forceinline__ float bf2f(unsigned short s) {
  uint32_t u = ((uint32_t)s) << 16;
  return __builtin_bit_cast(float, u);
}

// ---- pack x,h (f32) -> xh bf16 [8192][2048]
__global__ void pack_xh(const float* __restrict__ x, const float* __restrict__ h,
                        unsigned short* __restrict__ xh) {
  const int n4 = (8192 * 1024) / 4;
  const float4* x4 = (const float4*)x;
  const float4* h4 = (const float4*)h;
  for (int idx = blockIdx.x * blockDim.x + threadIdx.x; idx < n4;
       idx += gridDim.x * blockDim.x) {
    float4 vx = x4[idx];
    float4 vh = h4[idx];
    int row = idx >> 8;
    int c = (idx & 255) << 2;
    ushort4 px = { f2bf(vx.x), f2bf(vx.y), f2bf(vx.z), f2bf(vx.w) };
    ushort4 ph = { f2bf(vh.x), f2bf(vh.y), f2bf(vh.z), f2bf(vh.w) };
    *(ushort4*)(xh + (size_t)row * 2048 + c) = px;
    *(ushort4*)(xh + (size_t)row * 2048 + 1024 + c) = ph;
  }
}

// ---- all six W (K x N f32) -> bf16 Bt (N x K) transposes in one launch
__global__ void transpose_pack6(const float* __restrict__ W0, const float* __restrict__ W1,
                                const float* __restrict__ W2, const float* __restrict__ W3,
                                const float* __restrict__ W4, const float* __restrict__ W5,
                                unsigned short* __restrict__ Bt1, unsigned short* __restrict__ Bt2) {
  __shared__ float t[32][33];
  const float* W; unsigned short* dst; int rowOff, colOff;
  switch (blockIdx.z) {
    case 0: W = W0; dst = Bt1; rowOff = 0;    colOff = 0;    break;
    case 1: W = W1; dst = Bt1; rowOff = 0;    colOff = 1024; break;
    case 2: W = W2; dst = Bt1; rowOff = 1024; colOff = 0;    break;
    case 3: W = W3; dst = Bt1; rowOff = 1024; colOff = 1024; break;
    case 4: W = W4; dst = Bt2; rowOff = 0;    colOff = 0;    break;
    default: W = W5; dst = Bt2; rowOff = 0;   colOff = 1024; break;
  }
  int n0 = blockIdx.x * 32, k0 = blockIdx.y * 32;
  for (int i = threadIdx.y; i < 32; i += 8)
    t[i][threadIdx.x] = W[(size_t)(k0 + i) * 1024 + n0 + threadIdx.x];
  __syncthreads();
  for (int i = threadIdx.y; i < 32; i += 8) {
    int n = n0 + i, k = k0 + threadIdx.x;
    dst[(size_t)(rowOff + n) * 2048 + colOff + k] = f2bf(t[threadIdx.x][i]);
  }
}

// ---- occupancy-overlap GEMM: BM=128, BK=32, 8 waves (2Mx4N of 64xBN/4),
// triple-buffered LDS, 1 phase per K-tile (16/8 MFMA), 1 barrier/phase,
// counted vmcnt(LOADS), T1 XCD chunk swizzle, T5 setprio.
// Grid: 1D 512 blocks = 2 blocks/CU (the overlap mechanism).
template <int EPI, int BN>
__global__ __launch_bounds__(512, 4) void gru_gemm_occ(
    const unsigned short* __restrict__ xh,
    const unsigned short* __restrict__ hrA,
    const unsigned short* __restrict__ Bt,
    const float* __restrict__ bias0,
    const float* __restrict__ bias1,
    const unsigned short* __restrict__ u_in,
    unsigned short* __restrict__ u_out,
    unsigned short* __restrict__ hr_out,
    float* __restrict__ out) {
  constexpr int WN = BN / 64;        // n-frags per wave: 4 (BN=256) / 2 (BN=128)
  constexpr int ABUF = 128 * 32 * 2; // 8 KB
  constexpr int BBUF = BN * 32 * 2;  // 16 / 8 KB
  constexpr int BUFSZ = ABUF + BBUF;
  constexpr int NKT = 64;            // 2048 / 32
  constexpr int BLOADS = BN / 128;   // 2 / 1
  constexpr int LOADS = 1 + BLOADS;  // per-thread gload per tile
  __shared__ __align__(128) char smem[3 * BUFSZ];  // 72 / 48 KB

  const int tid = threadIdx.x;
  const int l = tid & 63;
  const int wid = tid >> 6;
  const int wr = wid >> 2, wc = wid & 3;

  // T1: XCD chunk swizzle (512 blocks = 8 chunks of 64)
  const int d = blockIdx.x;
  const int s = ((d & 7) << 6) + (d >> 3);
  const int tx = s & 7, ty = s >> 3;     // 8 N-cols x 64 M-rows
  const int row0 = ty * 128;
  const int col0 = tx * BN;

  // staging source addressing (linear LDS dest; linear global src)
  const int srow = tid >> 2;             // 0..127
  const int scol = (tid & 3) << 4;       // byte offset within 64-B k-row
  const char* pAx = (const char*)xh + (size_t)(row0 + srow) * 4096 + scol;
  const char* pAh = (EPI == 1)
      ? (const char*)hrA + (size_t)(row0 + srow) * 2048 + scol
      : (const char*)xh;
  const char* pB = (const char*)Bt + (size_t)(col0 + srow) * 4096 + scol;

  auto stage = [&](int t, int buf) {
    const size_t dA = (size_t)buf * BUFSZ + (size_t)tid * 16;
    if (EPI == 1 && t >= 32) {
      __builtin_amdgcn_global_load_lds((const AS1 void*)(pAh + (size_t)(t - 32) * 64),
                                       (AS3 void*)(smem + dA), 16, 0, 0);
    } else {
      __builtin_amdgcn_global_load_lds((const AS1 void*)(pAx + (size_t)t * 64),
                                       (AS3 void*)(smem + dA), 16, 0, 0);
    }
    const size_t dB = (size_t)buf * BUFSZ + ABUF + (size_t)tid * 16;
#pragma unroll
    for (int jj = 0; jj < BLOADS; ++jj)
      __builtin_amdgcn_global_load_lds((const AS1 void*)(pB + (size_t)t * 64 + (size_t)jj * (128 * 4096)),
                                       (AS3 void*)(smem + dB + (size_t)jj * 8192), 16, 0, 0);
  };

  // fragment read addressing: A [128][32] bf16 rows=64B; B [BN][32]
  const int lm = l & 15, hi4 = l >> 4;
  const int aoff = (wr * 64 + lm) * 64 + hi4 * 16;
  const int boff = ABUF + (wc * (BN / 4) + lm) * 64 + hi4 * 16;

#define RD_A(BUF, M) (*(const bf16x8*)(smem + (size_t)(BUF) * BUFSZ + aoff + (M) * 1024))
#define RD_B(BUF, N) (*(const bf16x8*)(smem + (size_t)(BUF) * BUFSZ + boff + (N) * 1024))
#define MFMA_(D, AV, BV) D = __builtin_amdgcn_mfma_f32_16x16x32_bf16(AV, BV, D, 0, 0, 0)

  f32x4 acc[4][WN] = {};

  // ---- prologue: stage tiles 0,1; confirm tile0 (vmcnt == LOADS leaves tile1 in flight)
  stage(0, 0);
  stage(1, 1);
  asm volatile("s_waitcnt vmcnt(%0)" ::"i"(LOADS) : "memory");
  __builtin_amdgcn_s_barrier();
  asm volatile("" ::: "memory");

  int cur = 0;  // t % 3
  for (int t = 0; t < NKT; ++t) {
    const int sb = (cur >= 1) ? cur - 1 : 2;  // (t+2) % 3
    if (t + 2 < NKT) stage(t + 2, sb);

    bf16x8 a[4], b[WN];
#pragma unroll
    for (int m = 0; m < 4; ++m) a[m] = RD_A(cur, m);
#pragma unroll
    for (int n = 0; n < WN; ++n) b[n] = RD_B(cur, n);

    __builtin_amdgcn_s_setprio(1);
#pragma unroll
    for (int m = 0; m < 4; ++m)
#pragma unroll
      for (int n = 0; n < WN; ++n) MFMA_(acc[m][n], a[m], b[n]);
    __builtin_amdgcn_s_setprio(0);

    if (t + 2 < NKT)      asm volatile("s_waitcnt vmcnt(%0)" ::"i"(LOADS) : "memory");
    else if (t + 1 < NKT) asm volatile("s_waitcnt vmcnt(0)" ::: "memory");
    __builtin_amdgcn_s_barrier();
    asm volatile("" ::: "memory");

    cur = (cur == 2) ? 0 : cur + 1;
  }

  // ---- epilogue: C/D layout col=lane&15, row=(lane>>4)*4+j
#pragma unroll
  for (int m = 0; m < 4; ++m) {
#pragma unroll
    for (int n = 0; n < WN; ++n) {
      const int col = col0 + wc * (BN / 4) + n * 16 + lm;
      const int rowb = row0 + wr * 64 + m * 16 + hi4 * 4;
#pragma unroll
      for (int j = 0; j < 4; ++j) {
        const int row = rowb + j;
        float v = acc[m][n][j];
        if (EPI == 0) {
          if (col < 1024) {
            float uv = 1.f / (1.f + __expf(-(v + bias0[col])));
            u_out[(size_t)row * 1024 + col] = f2bf(uv);
          } else {
            int c2 = col - 1024;
            float rv = 1.f / (1.f + __expf(-(v + bias1[c2])));
            float hv = bf2f(xh[(size_t)row * 2048 + 1024 + c2]);
            hr_out[(size_t)row * 1024 + c2] = f2bf(hv * rv);
          }
        } else {
          float e2x = __expf(2.f * (v + bias0[col]));
          float cp = (e2x - 1.f) / (e2x + 1.f);
          float uv = bf2f(u_in[(size_t)row * 1024 + col]);
          float hv = bf2f(xh[(size_t)row * 2048 + 1024 + col]);
          out[(size_t)row * 1024 + col] = uv * cp + (1.f - uv) * hv;
        }
      }
    }
  }
#undef RD_A
#undef RD_B
#undef MFMA_
}

extern "C" void kernel_launch(void* const* d_in, const int* in_sizes, int n_in,
                              void* d_out, int out_size, void* d_ws, size_t ws_size,
                              hipStream_t stream) {
  const float* x   = (const float*)d_in[0];
  const float* h   = (const float*)d_in[1];
  const float* Wxu = (const float*)d_in[2];
  const float* Whu = (const float*)d_in[3];
  const float* bu  = (const float*)d_in[4];
  const float* Wxr = (const float*)d_in[5];
  const float* Whr = (const float*)d_in[6];
  const float* br  = (const float*)d_in[7];
  const float* Wxc = (const float*)d_in[8];
  const float* Whc = (const float*)d_in[9];
  const float* bc  = (const float*)d_in[10];
  float* out = (float*)d_out;

  char* ws = (char*)d_ws;
  unsigned short* xh  = (unsigned short*)(ws);              // 33,554,432 B
  unsigned short* Bt1 = (unsigned short*)(ws + 33554432);   //  8,388,608 B
  unsigned short* Bt2 = (unsigned short*)(ws + 41943040);   //  4,194,304 B
  unsigned short* ubf = (unsigned short*)(ws + 46137344);   // 16,777,216 B
  unsigned short* hrb = (unsigned short*)(ws + 62914560);   // 16,777,216 B

  pack_xh<<<4096, 256, 0, stream>>>(x, h, xh);
  transpose_pack6<<<dim3(32, 32, 6), dim3(32, 8), 0, stream>>>(Wxu, Whu, Wxr, Whr, Wxc, Whc, Bt1, Bt2);

  // GEMM1: [x|h](8192x2048) @ Bt1 -> u (bf16), hr=h*r (bf16).  512 blocks = 2/CU.
  gru_gemm_occ<0, 256><<<512, 512, 0, stream>>>(xh, nullptr, Bt1, bu, br,
                                                nullptr, ubf, hrb, nullptr);
  // GEMM2: [x|hr](8192x2048) @ Bt2 -> out f32.  512 blocks = 2/CU.
  gru_gemm_occ<1, 128><<<512, 512, 0, stream>>>(xh, hrb, Bt2, bc, nullptr,
                                                ubf, nullptr, nullptr, out);
}

// Round 11
// 159.928 us; speedup vs baseline: 1.0116x; 1.0116x over previous
//
#include <hip/hip_runtime.h>
#include <stdint.h>

typedef float f32x4 __attribute__((ext_vector_type(4)));
typedef __bf16 bf16x8 __attribute__((ext_vector_type(8)));

#define AS1 __attribute__((address_space(1)))
#define AS3 __attribute__((address_space(3)))

__device__ __forceinline__ unsigned short f2bf(float f) {
  uint32_t u = __builtin_bit_cast(uint32_t, f);
  return (unsigned short)((u + 0x7fffu + ((u >> 16) & 1u)) >> 16);
}
__device__ __forceinline__ float bf2f(unsigned short s) {
  uint32_t u = ((uint32_t)s) << 16;
  return __builtin_bit_cast(float, u);
}

// ---- pack x,h (f32) -> xh bf16 [8192][2048]
__global__ void pack_xh(const float* __restrict__ x, const float* __restrict__ h,
                        unsigned short* __restrict__ xh) {
  const int n4 = (8192 * 1024) / 4;
  const float4* x4 = (const float4*)x;
  const float4* h4 = (const float4*)h;
  for (int idx = blockIdx.x * blockDim.x + threadIdx.x; idx < n4;
       idx += gridDim.x * blockDim.x) {
    float4 vx = x4[idx];
    float4 vh = h4[idx];
    int row = idx >> 8;
    int c = (idx & 255) << 2;
    ushort4 px = { f2bf(vx.x), f2bf(vx.y), f2bf(vx.z), f2bf(vx.w) };
    ushort4 ph = { f2bf(vh.x), f2bf(vh.y), f2bf(vh.z), f2bf(vh.w) };
    *(ushort4*)(xh + (size_t)row * 2048 + c) = px;
    *(ushort4*)(xh + (size_t)row * 2048 + 1024 + c) = ph;
  }
}

// ---- all six W (K x N f32) -> bf16 Bt (N x K) transposes in one launch
__global__ void transpose_pack6(const float* __restrict__ W0, const float* __restrict__ W1,
                                const float* __restrict__ W2, const float* __restrict__ W3,
                                const float* __restrict__ W4, const float* __restrict__ W5,
                                unsigned short* __restrict__ Bt1, unsigned short* __restrict__ Bt2) {
  __shared__ float t[32][33];
  const float* W; unsigned short* dst; int rowOff, colOff;
  switch (blockIdx.z) {
    case 0: W = W0; dst = Bt1; rowOff = 0;    colOff = 0;    break;
    case 1: W = W1; dst = Bt1; rowOff = 0;    colOff = 1024; break;
    case 2: W = W2; dst = Bt1; rowOff = 1024; colOff = 0;    break;
    case 3: W = W3; dst = Bt1; rowOff = 1024; colOff = 1024; break;
    case 4: W = W4; dst = Bt2; rowOff = 0;    colOff = 0;    break;
    default: W = W5; dst = Bt2; rowOff = 0;   colOff = 1024; break;
  }
  int n0 = blockIdx.x * 32, k0 = blockIdx.y * 32;
  for (int i = threadIdx.y; i < 32; i += 8)
    t[i][threadIdx.x] = W[(size_t)(k0 + i) * 1024 + n0 + threadIdx.x];
  __syncthreads();
  for (int i = threadIdx.y; i < 32; i += 8) {
    int n = n0 + i, k = k0 + threadIdx.x;
    dst[(size_t)(rowOff + n) * 2048 + colOff + k] = f2bf(t[threadIdx.x][i]);
  }
}

// ---- occupancy-overlap GEMM: BM=128, BK=32, 8 waves (2Mx4N), triple-buffered,
// 1 phase/K-tile, counted vmcnt(LOADS), T1 XCD chunk swizzle, T5 setprio,
// 64B-row LDS swizzle chunk^=((row>>1)&3) on BOTH stage-src and ds_read.
// Grid: 1D 512 blocks = 2 blocks/CU.
template <int EPI, int BN>
__global__ __launch_bounds__(512, 4) void gru_gemm_occ(
    const unsigned short* __restrict__ xh,
    const unsigned short* __restrict__ hrA,
    const unsigned short* __restrict__ Bt,
    const float* __restrict__ bias0,
    const float* __restrict__ bias1,
    const unsigned short* __restrict__ u_in,
    unsigned short* __restrict__ u_out,
    unsigned short* __restrict__ hr_out,
    float* __restrict__ out) {
  constexpr int WN = BN / 64;        // 4 (BN=256) / 2 (BN=128)
  constexpr int ABUF = 128 * 32 * 2; // 8 KB
  constexpr int BBUF = BN * 32 * 2;  // 16 / 8 KB
  constexpr int BUFSZ = ABUF + BBUF;
  constexpr int NKT = 64;            // 2048 / 32
  constexpr int BLOADS = BN / 128;   // 2 / 1
  constexpr int LOADS = 1 + BLOADS;
  __shared__ __align__(128) char smem[3 * BUFSZ];  // 72 / 48 KB

  const int tid = threadIdx.x;
  const int l = tid & 63;
  const int wid = tid >> 6;
  const int wr = wid >> 2, wc = wid & 3;

  // T1: XCD chunk swizzle (512 blocks = 8 chunks of 64)
  const int d = blockIdx.x;
  const int s = ((d & 7) << 6) + (d >> 3);
  const int tx = s & 7, ty = s >> 3;
  const int row0 = ty * 128;
  const int col0 = tx * BN;

  // staging: linear LDS dest; INVERSE-swizzled global source chunk
  const int srow = tid >> 2;                           // 0..127 (64-B row)
  const int schunk = (tid & 3) ^ ((srow >> 1) & 3);    // swizzled 16-B slot
  const char* pAx = (const char*)xh + (size_t)(row0 + srow) * 4096 + schunk * 16;
  const char* pAh = (EPI == 1)
      ? (const char*)hrA + (size_t)(row0 + srow) * 2048 + schunk * 16
      : (const char*)xh;
  const char* pB = (const char*)Bt + (size_t)(col0 + srow) * 4096 + schunk * 16;

  auto stage = [&](int t, int buf) {
    const size_t dA = (size_t)buf * BUFSZ + (size_t)tid * 16;
    if (EPI == 1 && t >= 32) {
      __builtin_amdgcn_global_load_lds((const AS1 void*)(pAh + (size_t)(t - 32) * 64),
                                       (AS3 void*)(smem + dA), 16, 0, 0);
    } else {
      __builtin_amdgcn_global_load_lds((const AS1 void*)(pAx + (size_t)t * 64),
                                       (AS3 void*)(smem + dA), 16, 0, 0);
    }
    const size_t dB = (size_t)buf * BUFSZ + ABUF + (size_t)tid * 16;
#pragma unroll
    for (int jj = 0; jj < BLOADS; ++jj)
      __builtin_amdgcn_global_load_lds((const AS1 void*)(pB + (size_t)t * 64 + (size_t)jj * (128 * 4096)),
                                       (AS3 void*)(smem + dB + (size_t)jj * 8192), 16, 0, 0);
  };

  // fragment reads: row stride 64 B; swizzled chunk = hi4 ^ ((lm>>1)&3)
  // (fragment row = base + m*16 + lm; base,m*16 are ≡0 in (row>>1)&3)
  const int lm = l & 15, hi4 = l >> 4;
  const int swz = (lm >> 1) & 3;
  const int rch = (hi4 ^ swz) * 16;
  const int aoff = (wr * 64 + lm) * 64 + rch;
  const int boff = ABUF + (wc * (BN / 4) + lm) * 64 + rch;

#define RD_A(BUF, M) (*(const bf16x8*)(smem + (size_t)(BUF) * BUFSZ + aoff + (M) * 1024))
#define RD_B(BUF, N) (*(const bf16x8*)(smem + (size_t)(BUF) * BUFSZ + boff + (N) * 1024))
#define MFMA_(D, AV, BV) D = __builtin_amdgcn_mfma_f32_16x16x32_bf16(AV, BV, D, 0, 0, 0)

  f32x4 acc[4][WN] = {};

  // ---- prologue: stage tiles 0,1; confirm tile0 (tile1 stays in flight)
  stage(0, 0);
  stage(1, 1);
  asm volatile("s_waitcnt vmcnt(%0)" ::"i"(LOADS) : "memory");
  __builtin_amdgcn_s_barrier();
  asm volatile("" ::: "memory");

  int cur = 0;
  for (int t = 0; t < NKT; ++t) {
    const int sb = (cur >= 1) ? cur - 1 : 2;  // (t+2) % 3
    if (t + 2 < NKT) stage(t + 2, sb);

    bf16x8 a[4], b[WN];
#pragma unroll
    for (int m = 0; m < 4; ++m) a[m] = RD_A(cur, m);
#pragma unroll
    for (int n = 0; n < WN; ++n) b[n] = RD_B(cur, n);

    __builtin_amdgcn_s_setprio(1);
#pragma unroll
    for (int m = 0; m < 4; ++m)
#pragma unroll
      for (int n = 0; n < WN; ++n) MFMA_(acc[m][n], a[m], b[n]);
    __builtin_amdgcn_s_setprio(0);

    if (t + 2 < NKT)      asm volatile("s_waitcnt vmcnt(%0)" ::"i"(LOADS) : "memory");
    else if (t + 1 < NKT) asm volatile("s_waitcnt vmcnt(0)" ::: "memory");
    __builtin_amdgcn_s_barrier();
    asm volatile("" ::: "memory");

    cur = (cur == 2) ? 0 : cur + 1;
  }

  // ---- epilogue: C/D layout col=lane&15, row=(lane>>4)*4+j
#pragma unroll
  for (int m = 0; m < 4; ++m) {
#pragma unroll
    for (int n = 0; n < WN; ++n) {
      const int col = col0 + wc * (BN / 4) + n * 16 + lm;
      const int rowb = row0 + wr * 64 + m * 16 + hi4 * 4;
#pragma unroll
      for (int j = 0; j < 4; ++j) {
        const int row = rowb + j;
        float v = acc[m][n][j];
        if (EPI == 0) {
          if (col < 1024) {
            float uv = 1.f / (1.f + __expf(-(v + bias0[col])));
            u_out[(size_t)row * 1024 + col] = f2bf(uv);
          } else {
            int c2 = col - 1024;
            float rv = 1.f / (1.f + __expf(-(v + bias1[c2])));
            float hv = bf2f(xh[(size_t)row * 2048 + 1024 + c2]);
            hr_out[(size_t)row * 1024 + c2] = f2bf(hv * rv);
          }
        } else {
          float e2x = __expf(2.f * (v + bias0[col]));
          float cp = (e2x - 1.f) / (e2x + 1.f);
          float uv = bf2f(u_in[(size_t)row * 1024 + col]);
          float hv = bf2f(xh[(size_t)row * 2048 + 1024 + col]);
          out[(size_t)row * 1024 + col] = uv * cp + (1.f - uv) * hv;
        }
      }
    }
  }
#undef RD_A
#undef RD_B
#undef MFMA_
}

extern "C" void kernel_launch(void* const* d_in, const int* in_sizes, int n_in,
                              void* d_out, int out_size, void* d_ws, size_t ws_size,
                              hipStream_t stream) {
  const float* x   = (const float*)d_in[0];
  const float* h   = (const float*)d_in[1];
  const float* Wxu = (const float*)d_in[2];
  const float* Whu = (const float*)d_in[3];
  const float* bu  = (const float*)d_in[4];
  const float* Wxr = (const float*)d_in[5];
  const float* Whr = (const float*)d_in[6];
  const float* br  = (const float*)d_in[7];
  const float* Wxc = (const float*)d_in[8];
  const float* Whc = (const float*)d_in[9];
  const float* bc  = (const float*)d_in[10];
  float* out = (float*)d_out;

  char* ws = (char*)d_ws;
  unsigned short* xh  = (unsigned short*)(ws);              // 33,554,432 B
  unsigned short* Bt1 = (unsigned short*)(ws + 33554432);   //  8,388,608 B
  unsigned short* Bt2 = (unsigned short*)(ws + 41943040);   //  4,194,304 B
  unsigned short* ubf = (unsigned short*)(ws + 46137344);   // 16,777,216 B
  unsigned short* hrb = (unsigned short*)(ws + 62914560);   // 16,777,216 B

  pack_xh<<<4096, 256, 0, stream>>>(x, h, xh);
  transpose_pack6<<<dim3(32, 32, 6), dim3(32, 8), 0, stream>>>(Wxu, Whu, Wxr, Whr, Wxc, Whc, Bt1, Bt2);

  // GEMM1: [x|h](8192x2048) @ Bt1 -> u (bf16), hr=h*r (bf16).  512 blocks = 2/CU.
  gru_gemm_occ<0, 256><<<512, 512, 0, stream>>>(xh, nullptr, Bt1, bu, br,
                                                nullptr, ubf, hrb, nullptr);
  // GEMM2: [x|hr](8192x2048) @ Bt2 -> out f32.  512 blocks = 2/CU.
  gru_gemm_occ<1, 128><<<512, 512, 0, stream>>>(xh, hrb, Bt2, bc, nullptr,
                                                ubf, nullptr, nullptr, out);
}

// Round 12
// 156.048 us; speedup vs baseline: 1.0368x; 1.0249x over previous
//
#include <hip/hip_runtime.h>
#include <stdint.h>

typedef float f32x4 __attribute__((ext_vector_type(4)));
typedef __bf16 bf16x8 __attribute__((ext_vector_type(8)));

#define AS1 __attribute__((address_space(1)))
#define AS3 __attribute__((address_space(3)))

__device__ __forceinline__ unsigned short f2bf(float f) {
  uint32_t u = __builtin_bit_cast(uint32_t, f);
  return (unsigned short)((u + 0x7fffu + ((u >> 16) & 1u)) >> 16);
}
__device__ __forceinline__ float bf2f(unsigned short s) {
  uint32_t u = ((uint32_t)s) << 16;
  return __builtin_bit_cast(float, u);
}

// ---- merged prep: blocks 0..4095 pack x,h -> xh bf16 [8192][2048];
// blocks 4096..10239 transpose-pack the six 1024x1024 f32 W into Bt1/Bt2 (N x K bf16).
__global__ __launch_bounds__(256) void prep_all(
    const float* __restrict__ x, const float* __restrict__ h,
    const float* __restrict__ W0, const float* __restrict__ W1,
    const float* __restrict__ W2, const float* __restrict__ W3,
    const float* __restrict__ W4, const float* __restrict__ W5,
    unsigned short* __restrict__ xh,
    unsigned short* __restrict__ Bt1, unsigned short* __restrict__ Bt2) {
  const int b = blockIdx.x;
  if (b < 4096) {
    const int n4 = (8192 * 1024) / 4;
    const float4* x4 = (const float4*)x;
    const float4* h4 = (const float4*)h;
    for (int idx = b * 256 + threadIdx.x; idx < n4; idx += 4096 * 256) {
      float4 vx = x4[idx];
      float4 vh = h4[idx];
      int row = idx >> 8;
      int c = (idx & 255) << 2;
      ushort4 px = { f2bf(vx.x), f2bf(vx.y), f2bf(vx.z), f2bf(vx.w) };
      ushort4 ph = { f2bf(vh.x), f2bf(vh.y), f2bf(vh.z), f2bf(vh.w) };
      *(ushort4*)(xh + (size_t)row * 2048 + c) = px;
      *(ushort4*)(xh + (size_t)row * 2048 + 1024 + c) = ph;
    }
    return;
  }
  __shared__ float t[32][33];
  const int z = (b - 4096) >> 10;          // 0..5
  const int ti = (b - 4096) & 1023;
  const float* W; unsigned short* dst; int rowOff, colOff;
  switch (z) {
    case 0: W = W0; dst = Bt1; rowOff = 0;    colOff = 0;    break;
    case 1: W = W1; dst = Bt1; rowOff = 0;    colOff = 1024; break;
    case 2: W = W2; dst = Bt1; rowOff = 1024; colOff = 0;    break;
    case 3: W = W3; dst = Bt1; rowOff = 1024; colOff = 1024; break;
    case 4: W = W4; dst = Bt2; rowOff = 0;    colOff = 0;    break;
    default: W = W5; dst = Bt2; rowOff = 0;   colOff = 1024; break;
  }
  const int n0 = (ti & 31) * 32, k0 = (ti >> 5) * 32;
  const int tx = threadIdx.x & 31, ty = threadIdx.x >> 5;
  for (int i = ty; i < 32; i += 8)
    t[i][tx] = W[(size_t)(k0 + i) * 1024 + n0 + tx];
  __syncthreads();
  for (int i = ty; i < 32; i += 8) {
    int n = n0 + i, k = k0 + tx;
    dst[(size_t)(rowOff + n) * 2048 + colOff + k] = f2bf(t[tx][i]);
  }
}

// ---- 8-phase GEMM, BALANCED all-late ds_reads (4,8,8,4,4,8,8,4 per phase),
// checkpoints at ph2/ph6 (VCNT=4), T1 XCD chunk swizzle, T2 both-sides LDS
// swizzle, T5 setprio, slab-aligned wave ownership.
// BM=256, BK=64, 8 waves (2Mx4N), 2 K-tiles/iter. Grid: 1D, 256 blocks.
template <int EPI, int BN>
__global__ __launch_bounds__(512, 1) void gru_gemm8(
    const unsigned short* __restrict__ xh,
    const unsigned short* __restrict__ hrA,
    const unsigned short* __restrict__ Bt,
    const float* __restrict__ bias0,
    const float* __restrict__ bias1,
    const unsigned short* __restrict__ u_in,
    unsigned short* __restrict__ u_out,
    unsigned short* __restrict__ hr_out,
    float* __restrict__ out) {
  constexpr int WN = BN / 64;
  constexpr int NH = WN / 2;
  constexpr int ABUF = 32768;
  constexpr int BBUF = BN * 128;
  constexpr int BUFSZ = ABUF + BBUF;
  constexpr int NKT = 32;
  constexpr int NIT = NKT / 2;
  constexpr int VCNT = 4;
  __shared__ __align__(128) char smem[2 * BUFSZ];

  const int tid = threadIdx.x;
  const int l = tid & 63;
  const int wid = tid >> 6;
  const int wr = wid >> 2, wc = wid & 3;

  // T1: XCD chunk swizzle (256 blocks = 8 chunks of 32)
  const int d = blockIdx.x;
  const int s = ((d & 7) << 5) + (d >> 3);
  const int tx = s & 7, ty = s >> 3;
  const int row0 = ty * 256;
  const int col0 = tx * BN;

  // staging source (inverse-swizzled global addr; LDS dest linear)
  const int srow = tid >> 3;
  const int s0 = (tid & 7) ^ (srow & 7);
  const char* pAx = (const char*)xh + (size_t)(row0 + srow) * 4096 + s0 * 16;
  const char* pAh = (EPI == 1)
      ? (const char*)hrA + (size_t)(row0 + srow) * 2048 + s0 * 16
      : (const char*)xh;
  const char* pB = (const char*)Bt + (size_t)(col0 + srow) * 4096 + s0 * 16;

  auto stage_A = [&](int t, int half, int p) {
    if (t >= NKT) return;
    const size_t dd = (size_t)p * BUFSZ + (size_t)half * 16384 + (size_t)tid * 16;
    if (EPI == 1 && t >= 16) {
      const char* sp = pAh + (size_t)(t - 16) * 128 + (size_t)half * (128 * 2048);
#pragma unroll
      for (int jj = 0; jj < 2; ++jj)
        __builtin_amdgcn_global_load_lds((const AS1 void*)(sp + (size_t)jj * (64 * 2048)),
                                         (AS3 void*)(smem + dd + (size_t)jj * 8192), 16, 0, 0);
    } else {
      const char* sp = pAx + (size_t)t * 128 + (size_t)half * (128 * 4096);
#pragma unroll
      for (int jj = 0; jj < 2; ++jj)
        __builtin_amdgcn_global_load_lds((const AS1 void*)(sp + (size_t)jj * (64 * 4096)),
                                         (AS3 void*)(smem + dd + (size_t)jj * 8192), 16, 0, 0);
    }
  };
  auto stage_B = [&](int t, int half, int p) {
    if (t >= NKT) return;
    const char* sp = pB + (size_t)t * 128 + (size_t)half * (128 * 4096);
    const size_t dd = (size_t)p * BUFSZ + ABUF + (size_t)half * 16384 + (size_t)tid * 16;
#pragma unroll
    for (int jj = 0; jj < 2; ++jj)
      __builtin_amdgcn_global_load_lds((const AS1 void*)(sp + (size_t)jj * (64 * 4096)),
                                       (AS3 void*)(smem + dd + (size_t)jj * 8192), 16, 0, 0);
  };

  // swizzled ds_read fragment addressing (slab-aligned ownership)
  const int lm = l & 15, hi4 = l >> 4;
  const int xorv = (l & 7) << 4;
  const int cb0 = (hi4 * 16) ^ xorv;
  const int cb1 = (64 + hi4 * 16) ^ xorv;
  const int aslab = (wr * 64 + lm) * 128;
  const int bslab = ABUF + (wc * 16 * NH + lm) * 128;

#define AROW(M) (((M) < 4) ? (M) * 16 : 128 + ((M) - 4) * 16)
#define BROW(N) (((N) < NH) ? (N) * 16 : BN / 2 + ((N) - NH) * 16)
#define RD_A(P, M, KS) (*(const bf16x8*)(smem + (size_t)(P) * BUFSZ + aslab + AROW(M) * 128 + ((KS) ? cb1 : cb0)))
#define RD_B(P, N, KS) (*(const bf16x8*)(smem + (size_t)(P) * BUFSZ + bslab + BROW(N) * 128 + ((KS) ? cb1 : cb0)))
#define MFMA_(D, AV, BV) D = __builtin_amdgcn_mfma_f32_16x16x32_bf16(AV, BV, D, 0, 0, 0)
#define LDA0(P) do { _Pragma("unroll") for (int m = 0; m < 4; ++m) { a0[m][0] = RD_A(P, m, 0); a0[m][1] = RD_A(P, m, 1); } } while (0)
#define LDA1(P) do { _Pragma("unroll") for (int m = 0; m < 4; ++m) { a1[m][0] = RD_A(P, 4 + m, 0); a1[m][1] = RD_A(P, 4 + m, 1); } } while (0)
#define LDB0(P) do { _Pragma("unroll") for (int n = 0; n < NH; ++n) { b0[n][0] = RD_B(P, n, 0); b0[n][1] = RD_B(P, n, 1); } } while (0)
#define LDB1(P) do { _Pragma("unroll") for (int n = 0; n < NH; ++n) { b1[n][0] = RD_B(P, NH + n, 0); b1[n][1] = RD_B(P, NH + n, 1); } } while (0)
#define Q00() do { _Pragma("unroll") for (int m = 0; m < 4; ++m) _Pragma("unroll") for (int n = 0; n < NH; ++n) { MFMA_(acc[m][n], a0[m][0], b0[n][0]); MFMA_(acc[m][n], a0[m][1], b0[n][1]); } } while (0)
#define Q01() do { _Pragma("unroll") for (int m = 0; m < 4; ++m) _Pragma("unroll") for (int n = 0; n < NH; ++n) { MFMA_(acc[m][NH + n], a0[m][0], b1[n][0]); MFMA_(acc[m][NH + n], a0[m][1], b1[n][1]); } } while (0)
#define Q11() do { _Pragma("unroll") for (int m = 0; m < 4; ++m) _Pragma("unroll") for (int n = 0; n < NH; ++n) { MFMA_(acc[4 + m][NH + n], a1[m][0], b1[n][0]); MFMA_(acc[4 + m][NH + n], a1[m][1], b1[n][1]); } } while (0)
#define Q10() do { _Pragma("unroll") for (int m = 0; m < 4; ++m) _Pragma("unroll") for (int n = 0; n < NH; ++n) { MFMA_(acc[4 + m][n], a1[m][0], b0[n][0]); MFMA_(acc[4 + m][n], a1[m][1], b0[n][1]); } } while (0)
#define SP1 __builtin_amdgcn_s_setprio(1)
#define SP0 __builtin_amdgcn_s_setprio(0)
#define BARF() do { __builtin_amdgcn_s_barrier(); asm volatile("" ::: "memory"); } while (0)

  f32x4 acc[8][WN] = {};
  bf16x8 a0[4][2], a1[4][2], b0[NH][2], b1[NH][2];

  // ---- prologue: stage tile0 fully + tile1 {Ah0,B(h0[,h1])}; confirm tile0;
  // pre-read tile0's a0,b0 so ph0 has zero sync reads.
  stage_A(0, 0, 0); stage_A(0, 1, 0); stage_B(0, 0, 0);
  if (BN == 256) stage_B(0, 1, 0);
  stage_A(1, 0, 1); stage_B(1, 0, 1);
  if (BN == 256) stage_B(1, 1, 1);
  asm volatile("s_waitcnt vmcnt(%0)" ::"i"(BN == 256 ? 6 : 4) : "memory");
  BARF();
  LDA0(0); LDB0(0);

  for (int it = 0; it < NIT; ++it) {
    const int o = 2 * it + 1, e2 = 2 * it + 2, o2 = 2 * it + 3;
    const bool last = (it == NIT - 1);

    // ph0: stage o.Ah1->buf1; Q00(e) [a0,b0 preloaded]; late: e.b1 [4]
    stage_A(o, 1, 1);
    SP1; Q00(); SP0;
    LDB1(0);
    BARF();

    // ph1: stage e2.Ah0->buf0; Q01(e); late: e.a1 [8]
    stage_A(e2, 0, 0);
    SP1; Q01(); SP0;
    LDA1(0);
    BARF();

    // ph2: stage e2.Bh0->buf0; Q11(e); checkpoint (confirms ALL of tile o);
    // late: o.a0 [8]
    stage_B(e2, 0, 0);
    SP1; Q11(); SP0;
    if (last) asm volatile("s_waitcnt vmcnt(0)" ::: "memory");
    else      asm volatile("s_waitcnt vmcnt(%0)" ::"i"(VCNT) : "memory");
    LDA0(1);
    BARF();

    // ph3: stage e2.Bh1->buf0 (BN=256); Q10(e); late: o.b0 [4]
    if (BN == 256) stage_B(e2, 1, 0);
    SP1; Q10(); SP0;
    LDB0(1);
    BARF();

    // ph4: stage e2.Ah1->buf0; Q00(o); late: o.b1 [4]
    stage_A(e2, 1, 0);
    SP1; Q00(); SP0;
    LDB1(1);
    BARF();

    // ph5: stage o2.Ah0->buf1; Q01(o); late: o.a1 [8]
    stage_A(o2, 0, 1);
    SP1; Q01(); SP0;
    LDA1(1);
    BARF();

    // ph6: stage o2.Bh0->buf1; Q11(o); checkpoint (confirms ALL of tile e2);
    // late: e2.a0 [8] (skip on last)
    stage_B(o2, 0, 1);
    SP1; Q11(); SP0;
    if (last) asm volatile("s_waitcnt vmcnt(0)" ::: "memory");
    else      asm volatile("s_waitcnt vmcnt(%0)" ::"i"(VCNT) : "memory");
    if (!last) LDA0(0);
    BARF();

    // ph7: stage o2.Bh1->buf1 (BN=256); Q10(o); late: e2.b0 [4] (skip on last)
    if (BN == 256) stage_B(o2, 1, 1);
    SP1; Q10(); SP0;
    if (!last) LDB0(0);
    BARF();
  }

  // ---- epilogue: C/D layout col=lane&15, row=(lane>>4)*4+j; slab ownership.
#pragma unroll
  for (int m = 0; m < 8; ++m) {
#pragma unroll
    for (int n = 0; n < WN; ++n) {
      const int col = col0 + wc * 16 * NH + BROW(n) + lm;
      const int rowb = row0 + wr * 64 + AROW(m) + hi4 * 4;
#pragma unroll
      for (int j = 0; j < 4; ++j) {
        const int row = rowb + j;
        float v = acc[m][n][j];
        if (EPI == 0) {
          if (col < 1024) {
            float uv = 1.f / (1.f + __expf(-(v + bias0[col])));
            u_out[(size_t)row * 1024 + col] = f2bf(uv);
          } else {
            int c2 = col - 1024;
            float rv = 1.f / (1.f + __expf(-(v + bias1[c2])));
            float hv = bf2f(xh[(size_t)row * 2048 + 1024 + c2]);
            hr_out[(size_t)row * 1024 + c2] = f2bf(hv * rv);
          }
        } else {
          float e2x = __expf(2.f * (v + bias0[col]));
          float cp = (e2x - 1.f) / (e2x + 1.f);
          float uv = bf2f(u_in[(size_t)row * 1024 + col]);
          float hv = bf2f(xh[(size_t)row * 2048 + 1024 + col]);
          out[(size_t)row * 1024 + col] = uv * cp + (1.f - uv) * hv;
        }
      }
    }
  }
#undef AROW
#undef BROW
#undef RD_A
#undef RD_B
#undef MFMA_
#undef LDA0
#undef LDA1
#undef LDB0
#undef LDB1
#undef Q00
#undef Q01
#undef Q11
#undef Q10
#undef SP1
#undef SP0
#undef BARF
}

extern "C" void kernel_launch(void* const* d_in, const int* in_sizes, int n_in,
                              void* d_out, int out_size, void* d_ws, size_t ws_size,
                              hipStream_t stream) {
  const float* x   = (const float*)d_in[0];
  const float* h   = (const float*)d_in[1];
  const float* Wxu = (const float*)d_in[2];
  const float* Whu = (const float*)d_in[3];
  const float* bu  = (const float*)d_in[4];
  const float* Wxr = (const float*)d_in[5];
  const float* Whr = (const float*)d_in[6];
  const float* br  = (const float*)d_in[7];
  const float* Wxc = (const float*)d_in[8];
  const float* Whc = (const float*)d_in[9];
  const float* bc  = (const float*)d_in[10];
  float* out = (float*)d_out;

  char* ws = (char*)d_ws;
  unsigned short* xh  = (unsigned short*)(ws);              // 33,554,432 B
  unsigned short* Bt1 = (unsigned short*)(ws + 33554432);   //  8,388,608 B
  unsigned short* Bt2 = (unsigned short*)(ws + 41943040);   //  4,194,304 B
  unsigned short* ubf = (unsigned short*)(ws + 46137344);   // 16,777,216 B
  unsigned short* hrb = (unsigned short*)(ws + 62914560);   // 16,777,216 B

  prep_all<<<10240, 256, 0, stream>>>(x, h, Wxu, Whu, Wxr, Whr, Wxc, Whc,
                                      xh, Bt1, Bt2);

  // GEMM1: [x|h](8192x2048) @ Bt1 -> u (bf16), hr=h*r (bf16)
  gru_gemm8<0, 256><<<256, 512, 0, stream>>>(xh, nullptr, Bt1, bu, br,
                                             nullptr, ubf, hrb, nullptr);
  // GEMM2: [x|hr](8192x2048) @ Bt2 -> out f32
  gru_gemm8<1, 128><<<256, 512, 0, stream>>>(xh, hrb, Bt2, bc, nullptr,
                                             ubf, nullptr, nullptr, out);
}